// Round 4
// baseline (90.570 us; speedup 1.0000x reference)
//
#include <hip/hip_runtime.h>

typedef float  f32x4  __attribute__((ext_vector_type(4)));
typedef __bf16 bf16x8 __attribute__((ext_vector_type(8)));

#define CC 384

__device__ __forceinline__ unsigned short f2bf(float f) {
  union { float f; unsigned int u; } x; x.f = f;
  unsigned int u = x.u;
  return (unsigned short)((u + 0x7fffu + ((u >> 16) & 1u)) >> 16);
}

__device__ __forceinline__ f32x4 mfma16(bf16x8 a, bf16x8 b, f32x4 c) {
  return __builtin_amdgcn_mfma_f32_16x16x32_bf16(a, b, c, 0, 0, 0);
}

// ---------------- kernel 0: repack W into B-fragment layout ----------------
// dst: [kk(0..11)][nt(0..11)][lane(0..63)][j(0..7)] bf16
// element (k, n): kk=k>>5, lane=((k>>3)&3)*16 + (n&15), j=k&7, nt=n>>4
__global__ void repack_w(const float* __restrict__ Wq, const float* __restrict__ Wk,
                         const float* __restrict__ Wv, unsigned short* __restrict__ wf) {
  int e = blockIdx.x * 512 + threadIdx.x;      // 73728 total, exact
  int k = e / 192;
  int n = e - k * 192;
  const float* W = (n < 64) ? Wq : (n < 128) ? Wk : Wv;
  float val = W[k * 64 + (n & 63)];
  int kk = k >> 5;
  int lane = (((k >> 3) & 3) << 4) | (n & 15);
  int j = k & 7;
  int nt = n >> 4;
  wf[(size_t)(((kk * 12 + nt) << 6) + lane) * 8 + j] = f2bf(val);
}

// ---------------- fused kernel: barrier-free projection + column-softmax attention --------
// one block per batch, 8 waves; wave w owns m-tiles {w, 15-w} (32 q-rows) for BOTH stages.
__global__ __launch_bounds__(512, 2) void fused(const float* __restrict__ x,
                                                const unsigned short* __restrict__ wf,
                                                float* __restrict__ out) {
  // LDS layout (119,808 B total) — untouched during projection:
  //  [0, 36864)        Sx[256][72] bf16  (q-scratch, then exp-weights)
  //  [36864, 73728)    kL[256][72] bf16
  //  [73728, 107520)   vT[64][264] bf16
  //  [107520, 119808)  pm/ps/gg [16][64] f32 each
  __shared__ __attribute__((aligned(16))) unsigned char smem[119808];
  unsigned short (*Sx)[72] = (unsigned short(*)[72])smem;
  unsigned short (*kL)[72] = (unsigned short(*)[72])(smem + 36864);
  unsigned short (*vT)[264] = (unsigned short(*)[264])(smem + 73728);
  float* pm = (float*)(smem + 107520);
  float* ps = pm + 1024;
  float* gg = ps + 1024;

  const int tid = threadIdx.x;
  const int w = tid >> 6, lane = tid & 63;
  const int l15 = lane & 15, lhi = lane >> 4;
  const int b = blockIdx.x;
  const int mts[2] = {w, 15 - w};

  // ================= projection (no barriers; per-wave software pipeline) =================
  const float* xr0 = x + ((size_t)b * 256 + mts[0] * 16 + l15) * CC + lhi * 8;
  const float* xr1 = x + ((size_t)b * 256 + mts[1] * 16 + l15) * CC + lhi * 8;
  const unsigned short* wl = wf + lane * 8;   // frag (ks,nt) at + (ks*12+nt)*512

  f32x4 zero = {0.f, 0.f, 0.f, 0.f};
  f32x4 acc[2][12];
#pragma unroll
  for (int i = 0; i < 2; ++i)
#pragma unroll
    for (int nt = 0; nt < 12; ++nt) acc[i][nt] = zero;

  {
    bf16x8 wreg[2][12];   // W double buffer (96 VGPR)
    f32x4  xreg[2][4];    // x double buffer (32 VGPR)

#define LOADW(kp_, s_) do {                                                     \
    _Pragma("unroll")                                                           \
    for (int nt_ = 0; nt_ < 12; ++nt_)                                          \
      wreg[s_][nt_] = *(const bf16x8*)(wl + ((kp_) * 12 + nt_) * 512);          \
  } while (0)
#define LOADX(kp_, s_) do {                                                     \
    const int o_ = (kp_) * 32;                                                  \
    xreg[s_][0] = *(const f32x4*)(xr0 + o_);                                    \
    xreg[s_][1] = *(const f32x4*)(xr0 + o_ + 4);                                \
    xreg[s_][2] = *(const f32x4*)(xr1 + o_);                                    \
    xreg[s_][3] = *(const f32x4*)(xr1 + o_ + 4);                                \
  } while (0)

    LOADW(0, 0);
    LOADX(0, 0);
#pragma unroll
    for (int kp = 0; kp < 12; ++kp) {
      const int cur = kp & 1, nxt = cur ^ 1;
      if (kp < 11) { LOADW(kp + 1, nxt); LOADX(kp + 1, nxt); }
#pragma unroll
      for (int i = 0; i < 2; ++i) {
        bf16x8 af;
#pragma unroll
        for (int j = 0; j < 4; ++j) {
          af[j]     = (__bf16)xreg[cur][2 * i][j];
          af[4 + j] = (__bf16)xreg[cur][2 * i + 1][j];
        }
#pragma unroll
        for (int nt = 0; nt < 12; ++nt) acc[i][nt] = mfma16(af, wreg[cur][nt], acc[i][nt]);
      }
    }
#undef LOADW
#undef LOADX
  }

  // epilogue: q (scaled) -> Sx scratch, k -> kL, v -> vT (transposed, packed b64)
  const float qs = 0.05103103630798288f;  // 384^-0.5
#pragma unroll
  for (int i = 0; i < 2; ++i) {
    const int rb = mts[i] * 16 + lhi * 4;
#pragma unroll
    for (int nt = 0; nt < 4; ++nt) {
      const int h = nt * 16 + l15;
#pragma unroll
      for (int r = 0; r < 4; ++r) Sx[rb + r][h] = f2bf(acc[i][nt][r] * qs);
    }
#pragma unroll
    for (int nt = 4; nt < 8; ++nt) {
      const int h = (nt - 4) * 16 + l15;
#pragma unroll
      for (int r = 0; r < 4; ++r) kL[rb + r][h] = f2bf(acc[i][nt][r]);
    }
#pragma unroll
    for (int nt = 8; nt < 12; ++nt) {
      const int h = (nt - 8) * 16 + l15;
      unsigned long long pk =
          (unsigned long long)f2bf(acc[i][nt][0]) |
          ((unsigned long long)f2bf(acc[i][nt][1]) << 16) |
          ((unsigned long long)f2bf(acc[i][nt][2]) << 32) |
          ((unsigned long long)f2bf(acc[i][nt][3]) << 48);
      *(unsigned long long*)&vT[h][rb] = pk;
    }
  }
  __syncthreads();  // q/k/v LDS-resident

  bf16x8 qf[2][2];
#pragma unroll
  for (int i = 0; i < 2; ++i)
#pragma unroll
    for (int kk = 0; kk < 2; ++kk)
      qf[i][kk] = *(const bf16x8*)&Sx[mts[i] * 16 + l15][kk * 32 + lhi * 8];

  // ================= attention =================
  f32x4 oacc[2][4];
#pragma unroll
  for (int i = 0; i < 2; ++i)
#pragma unroll
    for (int nh = 0; nh < 4; ++nh) oacc[i][nh] = zero;

  for (int p = 0; p < 4; ++p) {
    const int p4 = 4 * p;
    const bool any = (mts[1] >= p4);
    // ---- S compute + in-register tile-column stats + exp write ----
    if (any) {
      bf16x8 kf[4][2];
#pragma unroll
      for (int c = 0; c < 4; ++c)
#pragma unroll
        for (int kk = 0; kk < 2; ++kk)
          kf[c][kk] = *(const bf16x8*)&kL[p * 64 + c * 16 + l15][kk * 32 + lhi * 8];
#pragma unroll
      for (int i = 0; i < 2; ++i) {
        const int mt = mts[i];
        if (mt < p4) continue;
        const int cmax = mt - p4;
        const int rowb = mt * 16 + lhi * 4;
#pragma unroll
        for (int c = 0; c < 4; ++c) {
          const int cs = c * 16 + l15;
          if (c <= cmax) {
            f32x4 s = zero;
            s = mfma16(qf[i][0], kf[c][0], s);
            s = mfma16(qf[i][1], kf[c][1], s);
            const int cg = p * 64 + cs;
            const bool v0 = (rowb + 0) >= cg, v1 = (rowb + 1) >= cg;
            const bool v2 = (rowb + 2) >= cg, v3 = (rowb + 3) >= cg;
            float m = -1e30f;
            m = fmaxf(m, v0 ? s[0] : -1e30f);
            m = fmaxf(m, v1 ? s[1] : -1e30f);
            m = fmaxf(m, v2 ? s[2] : -1e30f);
            m = fmaxf(m, v3 ? s[3] : -1e30f);
            m = fmaxf(m, __shfl_xor(m, 16));
            m = fmaxf(m, __shfl_xor(m, 32));
            const float e0 = v0 ? __expf(s[0] - m) : 0.f;
            const float e1 = v1 ? __expf(s[1] - m) : 0.f;
            const float e2 = v2 ? __expf(s[2] - m) : 0.f;
            const float e3 = v3 ? __expf(s[3] - m) : 0.f;
            float t = e0 + e1 + e2 + e3;
            t += __shfl_xor(t, 16);
            t += __shfl_xor(t, 32);
            Sx[rowb + 0][cs] = f2bf(e0);
            Sx[rowb + 1][cs] = f2bf(e1);
            Sx[rowb + 2][cs] = f2bf(e2);
            Sx[rowb + 3][cs] = f2bf(e3);
            if (lhi == 0) { pm[mt * 64 + cs] = m; ps[mt * 64 + cs] = t; }
          } else {
            if (lhi == 0) { pm[mt * 64 + cs] = -1e30f; ps[mt * 64 + cs] = 0.f; }
          }
        }
      }
    }
    __syncthreads();  // B1: pm/ps/Sx stripe complete
    // ---- per-column reduce (redundant across waves; each wave writes its gg rows) ----
    {
      float M = -1e30f;
      for (int mt = p4; mt < 16; ++mt) M = fmaxf(M, pm[mt * 64 + lane]);
      float L = 0.f;
      for (int mt = p4; mt < 16; ++mt) L += ps[mt * 64 + lane] * __expf(pm[mt * 64 + lane] - M);
      const float rv = 1.0f / L;
      int mtw = p4 + w;
      if (mtw < 16) gg[mtw * 64 + lane] = __expf(pm[mtw * 64 + lane] - M) * rv;
      mtw += 8;
      if (mtw < 16) gg[mtw * 64 + lane] = __expf(pm[mtw * 64 + lane] - M) * rv;
    }
    __syncthreads();  // B2: gg ready
    // ---- W = Sx * gg, PV accumulate ----
    if (any) {
      bf16x8 vf[4][2];
#pragma unroll
      for (int nh = 0; nh < 4; ++nh)
#pragma unroll
        for (int kk = 0; kk < 2; ++kk)
          vf[nh][kk] = *(const bf16x8*)&vT[nh * 16 + l15][p * 64 + kk * 32 + lhi * 8];
#pragma unroll
      for (int i = 0; i < 2; ++i) {
        const int mt = mts[i];
        if (mt < p4) continue;
        const int grow = mt * 16 + l15;
        const int dmax = mt - p4;
#pragma unroll
        for (int kk = 0; kk < 2; ++kk) {
          if (kk == 1 && dmax <= 1) continue;  // upper half fully masked
          const int c0 = kk * 32 + lhi * 8;
          bf16x8 se = *(const bf16x8*)&Sx[grow][c0];
          f32x4 gA = *(const f32x4*)&gg[mt * 64 + c0];
          f32x4 gB = *(const f32x4*)&gg[mt * 64 + c0 + 4];
          const int cg0 = p * 64 + c0;
          bf16x8 wfr;
#pragma unroll
          for (int j = 0; j < 4; ++j)
            wfr[j] = (cg0 + j <= grow) ? (__bf16)((float)se[j] * gA[j]) : (__bf16)0.f;
#pragma unroll
          for (int j = 0; j < 4; ++j)
            wfr[4 + j] = (cg0 + 4 + j <= grow) ? (__bf16)((float)se[4 + j] * gB[j]) : (__bf16)0.f;
#pragma unroll
          for (int nh = 0; nh < 4; ++nh) oacc[i][nh] = mfma16(wfr, vf[nh][kk], oacc[i][nh]);
        }
      }
    }
  }
  // ---- output ----
#pragma unroll
  for (int i = 0; i < 2; ++i) {
    const int rb = mts[i] * 16 + lhi * 4;
#pragma unroll
    for (int nh = 0; nh < 4; ++nh) {
      const int h = nh * 16 + l15;
#pragma unroll
      for (int r = 0; r < 4; ++r)
        out[(size_t)b * 16384 + (size_t)(rb + r) * 64 + h] = oacc[i][nh][r];
    }
  }
}

extern "C" void kernel_launch(void* const* d_in, const int* in_sizes, int n_in,
                              void* d_out, int out_size, void* d_ws, size_t ws_size,
                              hipStream_t stream) {
  const float* x  = (const float*)d_in[0];
  const float* Wq = (const float*)d_in[1];
  const float* Wk = (const float*)d_in[2];
  const float* Wv = (const float*)d_in[3];
  float* out = (float*)d_out;

  unsigned short* wf = (unsigned short*)d_ws;   // 73728 bf16 frag-packed W

  repack_w<<<144, 512, 0, stream>>>(Wq, Wk, Wv, wf);
  fused<<<512, 512, 0, stream>>>(x, wf, out);
}